// Round 2
// baseline (1150.155 us; speedup 1.0000x reference)
//
#include <hip/hip_runtime.h>
#include <cstdint>
#include <cstddef>

// ---------------------------------------------------------------------------
// TGN transformer attention layer, MI355X (gfx950).
// Pipeline:
//   prep   : pack weights to fp16 (pad Wkv 356->384; fold time-ones into bq)
//   hist/scan/scatter : build CSR over dst (25k nodes, 500k edges)
//   k_q    : D rows : Q_ori -> Qh(f32), Kh_self, Vh_self (fp16)
//   k_kv   : E rows : X=[h|f|cos(dt*w)] -> K_ori -> Kh, Vh (fp16)   [dominant]
//   k_agg  : per-dst wave: exp(leaky(dot)) softmax-free-of-max, weighted V
//            aggregation, relu, LayerNorm -> d_out (f32)
// fp16 (e5m10) chosen over bf16: same MFMA rate on gfx950, 8x lower
// quantization noise; all tensor values are O(+-6) so e5m10 range is safe.
// ---------------------------------------------------------------------------

typedef _Float16 f16_t;
typedef _Float16 f16x8 __attribute__((ext_vector_type(8)));
typedef _Float16 f16x4 __attribute__((ext_vector_type(4)));
typedef float    f32x4 __attribute__((ext_vector_type(4)));

#define MFMA16(a, b, c) __builtin_amdgcn_mfma_f32_16x16x32_f16(a, b, c, 0, 0, 0)

static __device__ __forceinline__ f32x4 zero4() {
  f32x4 v; v[0] = 0.f; v[1] = 0.f; v[2] = 0.f; v[3] = 0.f; return v;
}

// w_j = 10^(-9 j / 99)  ->  exp2(j * (-9*log2(10)/99))
#define TIMEW_LOG2 (-0.30199346317157837f)

// ---------------------------------------------------------------------------
// prep: weight packing.  flat index ranges:
//   [0,98304)        Wkv_pad  f16 [256][384]  (zero-padded 356->384)
//   [98304,131072)   Wq_pack  f16 [256][128]  (h-columns of Wq_lin)
//   [131072,327680)  W3       f16 [768][256]  ([Wq;Wk;Wv])
//   [327680,327936)  bq_eff   f32 [256]  (bq_lin + sum of time-cols of Wq_lin)
// ---------------------------------------------------------------------------
__global__ void k_prep(const float* __restrict__ wq_lin,
                       const float* __restrict__ bq_lin,
                       const float* __restrict__ wkv_lin,
                       const float* __restrict__ wq,
                       const float* __restrict__ wk,
                       const float* __restrict__ wv,
                       f16_t* __restrict__ wkv_pad,
                       f16_t* __restrict__ wq1,
                       f16_t* __restrict__ w3,
                       float* __restrict__ bqe) {
  int i = blockIdx.x * 256 + threadIdx.x;
  if (i < 98304) {
    int o = i / 384, k = i - o * 384;
    wkv_pad[i] = (f16_t)(k < 356 ? wkv_lin[o * 356 + k] : 0.f);
  } else if (i < 131072) {
    int j = i - 98304;
    int o = j >> 7, k = j & 127;
    wq1[j] = (f16_t)wq_lin[o * 228 + k];
  } else if (i < 327680) {
    int j = i - 131072;
    int r = j >> 8, k = j & 255;
    const float* src = (r < 256) ? wq : ((r < 512) ? wk : wv);
    int rr = r & 255;
    w3[j] = (f16_t)src[rr * 256 + k];
  } else if (i < 327936) {
    int o = i - 327680;
    float s = bq_lin[o];
    for (int j = 0; j < 100; ++j) s += wq_lin[o * 228 + 128 + j];
    bqe[o] = s;
  }
}

// ---------------------------------------------------------------------------
// CSR build
// ---------------------------------------------------------------------------
__global__ void k_hist(const int* __restrict__ dst, int* __restrict__ rs, int E) {
  int e = blockIdx.x * 256 + threadIdx.x;
  if (e < E) atomicAdd(&rs[dst[e] + 1], 1);
}

__global__ void k_scan(int* __restrict__ rs, int* __restrict__ cur, int D) {
  __shared__ int sd[1024];
  __shared__ int srun;
  const int t = threadIdx.x;
  if (t == 0) srun = 0;
  __syncthreads();
  for (int base = 0; base < D; base += 1024) {
    const int i = base + t;
    int c = (i < D) ? rs[i + 1] : 0;
    sd[t] = c;
    __syncthreads();
    for (int off = 1; off < 1024; off <<= 1) {
      int v = (t >= off) ? sd[t - off] : 0;
      __syncthreads();
      sd[t] += v;
      __syncthreads();
    }
    const int incl = sd[t];
    const int run = srun;
    __syncthreads();
    if (i < D) {
      cur[i] = run + incl - c;     // exclusive prefix = cursor start
      rs[i + 1] = run + incl;      // inclusive prefix = row_start[i+1]
    }
    if (t == 1023) srun = run + sd[1023];
    __syncthreads();
  }
}

__global__ void k_scatter(const int* __restrict__ dst, int* __restrict__ cur,
                          int* __restrict__ csr, int E) {
  int e = blockIdx.x * 256 + threadIdx.x;
  if (e < E) {
    int pos = atomicAdd(&cur[dst[e]], 1);
    csr[pos] = e;
  }
}

__global__ void k_sentinel(float* __restrict__ o, int n) {
  int i = blockIdx.x * 256 + threadIdx.x;
  if (i < n) o[i] = 1e30f;  // unambiguous "workspace too small" marker
}

// ---------------------------------------------------------------------------
// k_q: 64 dst rows per block, 8 waves.
//   GEMM1 (K=128): Q_ori = h[:D] @ Wq_pack^T + bq_eff     -> LDS (f16, swz)
//   GEMM2 (3 passes over W3): Qh(f32), Kh_self, Vh_self (f16)
// LDS: X [64][128] aliased under Q_ori tile [64][256] (32 KB total).
// ---------------------------------------------------------------------------
__global__ __launch_bounds__(512) void k_q(
    const float* __restrict__ h, const float* __restrict__ bqe,
    const float* __restrict__ bq, const float* __restrict__ bk,
    const float* __restrict__ bv, const f16_t* __restrict__ wq1,
    const f16_t* __restrict__ w3, float* __restrict__ qhd,
    f16_t* __restrict__ khs, f16_t* __restrict__ vhs, int D) {
  __shared__ f16_t sm[64 * 256];
  f16_t* xs = sm;
  f16_t* ks = sm;
  const int tid = threadIdx.x;
  const int dbase = blockIdx.x * 64;

  // ---- stage X (h rows only; time part folded into bq_eff)
  {
    const int r = tid >> 3, q = tid & 7;
    const int dd = min(dbase + r, D - 1);
    const int sw = r & 7;
    const float* p = h + (size_t)dd * 128 + q * 16;
#pragma unroll
    for (int u = 0; u < 2; ++u) {
      float4 v0 = *(const float4*)(p + u * 8);
      float4 v1 = *(const float4*)(p + u * 8 + 4);
      f16x8 w8;
      w8[0] = (f16_t)v0.x; w8[1] = (f16_t)v0.y; w8[2] = (f16_t)v0.z; w8[3] = (f16_t)v0.w;
      w8[4] = (f16_t)v1.x; w8[5] = (f16_t)v1.y; w8[6] = (f16_t)v1.z; w8[7] = (f16_t)v1.w;
      *(f16x8*)&xs[r * 128 + (((2 * q + u) ^ sw) << 3)] = w8;
    }
  }
  __syncthreads();

  const int lane = tid & 63;
  const int wv_ = tid >> 6;
  const int m16 = lane & 15;
  const int g = lane >> 4;

  // ---- GEMM1: K = 128 (4 k-steps)
  f32x4 acc1[4][2];
#pragma unroll
  for (int mt = 0; mt < 4; ++mt)
#pragma unroll
    for (int nt = 0; nt < 2; ++nt) acc1[mt][nt] = zero4();

#pragma unroll
  for (int kt = 0; kt < 4; ++kt) {
    f16x8 a[4];
#pragma unroll
    for (int mt = 0; mt < 4; ++mt) {
      int row = mt * 16 + m16;
      a[mt] = *(const f16x8*)&xs[row * 128 + ((((kt << 2) + g) ^ (row & 7)) << 3)];
    }
#pragma unroll
    for (int nt = 0; nt < 2; ++nt) {
      int col = wv_ * 32 + nt * 16 + m16;
      f16x8 b = *(const f16x8*)&wq1[(size_t)col * 128 + (kt << 5) + (g << 3)];
#pragma unroll
      for (int mt = 0; mt < 4; ++mt) acc1[mt][nt] = MFMA16(a[mt], b, acc1[mt][nt]);
    }
  }
  __syncthreads();  // all X reads done; ks aliases xs

  // ---- write Q_ori tile (f16, swizzled) with folded bias
#pragma unroll
  for (int nt = 0; nt < 2; ++nt) {
    int col = wv_ * 32 + nt * 16 + m16;
    float bias = bqe[col];
#pragma unroll
    for (int mt = 0; mt < 4; ++mt)
#pragma unroll
      for (int j = 0; j < 4; ++j) {
        int row = mt * 16 + (g << 2) + j;
        ks[row * 256 + ((((col >> 3) ^ (row & 7)) << 3)) + (col & 7)] =
            (f16_t)(acc1[mt][nt][j] + bias);
      }
  }
  __syncthreads();

  // ---- GEMM2: 3 passes (Qh -> f32, Kh_self, Vh_self -> f16)
#pragma unroll
  for (int p = 0; p < 3; ++p) {
    const f16_t* wsec = w3 + ((size_t)p << 16);
    const float* bsec = (p == 0) ? bq : ((p == 1) ? bk : bv);
    f32x4 acc[4][2];
#pragma unroll
    for (int mt = 0; mt < 4; ++mt)
#pragma unroll
      for (int nt = 0; nt < 2; ++nt) acc[mt][nt] = zero4();
#pragma unroll
    for (int kt = 0; kt < 8; ++kt) {
      f16x8 a[4];
#pragma unroll
      for (int mt = 0; mt < 4; ++mt) {
        int row = mt * 16 + m16;
        a[mt] = *(const f16x8*)&ks[row * 256 + ((((kt << 2) + g) ^ (row & 7)) << 3)];
      }
#pragma unroll
      for (int nt = 0; nt < 2; ++nt) {
        int col = wv_ * 32 + nt * 16 + m16;
        f16x8 b = *(const f16x8*)&wsec[(size_t)col * 256 + (kt << 5) + (g << 3)];
#pragma unroll
        for (int mt = 0; mt < 4; ++mt) acc[mt][nt] = MFMA16(a[mt], b, acc[mt][nt]);
      }
    }
#pragma unroll
    for (int nt = 0; nt < 2; ++nt) {
      int col = wv_ * 32 + nt * 16 + m16;
      float bias = bsec[col];
#pragma unroll
      for (int mt = 0; mt < 4; ++mt)
#pragma unroll
        for (int j = 0; j < 4; ++j) {
          int row = mt * 16 + (g << 2) + j;
          int dd = dbase + row;
          if (dd < D) {
            float val = acc[mt][nt][j] + bias;
            if (p == 0)
              qhd[(size_t)dd * 256 + col] = val;      // keep Q in f32
            else if (p == 1)
              khs[(size_t)dd * 256 + col] = (f16_t)val;
            else
              vhs[(size_t)dd * 256 + col] = (f16_t)val;
          }
        }
    }
  }
}

// ---------------------------------------------------------------------------
// k_kv: 64 edge rows per block, 8 waves.  The dominant kernel.
//   stage X = [h_src(128) | f(128) | cos(dt*w)(100) | 0(28)]  f16, swizzled
//   GEMM1 (K=384): K_ori = X @ Wkv_pad^T + bkv  -> LDS (aliases X)
//   GEMM2 (2 passes): Kh = K_ori@Wk^T+bk, Vh = K_ori@Wv^T+bv -> global f16
// LDS: 64*384*2 = 48 KB  (K_ori tile 32 KB aliases the front of it)
// ---------------------------------------------------------------------------
__global__ __launch_bounds__(512) void k_kv(
    const float* __restrict__ h, const float* __restrict__ f,
    const float* __restrict__ dt, const float* __restrict__ bkv,
    const float* __restrict__ bk, const float* __restrict__ bv,
    const f16_t* __restrict__ wkv, const f16_t* __restrict__ w3,
    f16_t* __restrict__ khg, f16_t* __restrict__ vhg, int D, int E) {
  __shared__ f16_t sm[64 * 384];
  f16_t* xs = sm;
  f16_t* ks = sm;
  const int tid = threadIdx.x;
  const int ebase = blockIdx.x * 64;

  // ---- stage X
  {
    const int r = tid >> 3, q = tid & 7;
    const int e = min(ebase + r, E - 1);
    const int sw = r & 7;
    {
      const float* p = h + (size_t)(D + e) * 128 + q * 16;
#pragma unroll
      for (int u = 0; u < 2; ++u) {
        float4 v0 = *(const float4*)(p + u * 8);
        float4 v1 = *(const float4*)(p + u * 8 + 4);
        f16x8 w8;
        w8[0] = (f16_t)v0.x; w8[1] = (f16_t)v0.y; w8[2] = (f16_t)v0.z; w8[3] = (f16_t)v0.w;
        w8[4] = (f16_t)v1.x; w8[5] = (f16_t)v1.y; w8[6] = (f16_t)v1.z; w8[7] = (f16_t)v1.w;
        *(f16x8*)&xs[r * 384 + (((2 * q + u) ^ sw) << 3)] = w8;
      }
    }
    {
      const float* p = f + (size_t)e * 128 + q * 16;
#pragma unroll
      for (int u = 0; u < 2; ++u) {
        float4 v0 = *(const float4*)(p + u * 8);
        float4 v1 = *(const float4*)(p + u * 8 + 4);
        f16x8 w8;
        w8[0] = (f16_t)v0.x; w8[1] = (f16_t)v0.y; w8[2] = (f16_t)v0.z; w8[3] = (f16_t)v0.w;
        w8[4] = (f16_t)v1.x; w8[5] = (f16_t)v1.y; w8[6] = (f16_t)v1.z; w8[7] = (f16_t)v1.w;
        *(f16x8*)&xs[r * 384 + (((16 + 2 * q + u) ^ sw) << 3)] = w8;
      }
    }
    {
      const float dtv = dt[e];
#pragma unroll
      for (int c = q; c < 128; c += 8) {
        float val = 0.f;
        if (c < 100) {
          float wj = exp2f(TIMEW_LOG2 * (float)c);
          val = cosf(dtv * wj);
        }
        int col = 256 + c;
        xs[r * 384 + (((col >> 3) ^ sw) << 3) + (col & 7)] = (f16_t)val;
      }
    }
  }
  __syncthreads();

  const int lane = tid & 63;
  const int wv_ = tid >> 6;
  const int m16 = lane & 15;
  const int g = lane >> 4;

  // ---- GEMM1: K = 384 (12 k-steps)
  f32x4 acc1[4][2];
#pragma unroll
  for (int mt = 0; mt < 4; ++mt)
#pragma unroll
    for (int nt = 0; nt < 2; ++nt) acc1[mt][nt] = zero4();

#pragma unroll
  for (int kt = 0; kt < 12; ++kt) {
    f16x8 a[4];
#pragma unroll
    for (int mt = 0; mt < 4; ++mt) {
      int row = mt * 16 + m16;
      a[mt] = *(const f16x8*)&xs[row * 384 + ((((kt << 2) + g) ^ (row & 7)) << 3)];
    }
#pragma unroll
    for (int nt = 0; nt < 2; ++nt) {
      int col = wv_ * 32 + nt * 16 + m16;
      f16x8 b = *(const f16x8*)&wkv[(size_t)col * 384 + (kt << 5) + (g << 3)];
#pragma unroll
      for (int mt = 0; mt < 4; ++mt) acc1[mt][nt] = MFMA16(a[mt], b, acc1[mt][nt]);
    }
  }
  __syncthreads();  // all X reads done; ks aliases xs

  // ---- write K_ori tile (f16, swizzled) + bkv bias
#pragma unroll
  for (int nt = 0; nt < 2; ++nt) {
    int col = wv_ * 32 + nt * 16 + m16;
    float bias = bkv[col];
#pragma unroll
    for (int mt = 0; mt < 4; ++mt)
#pragma unroll
      for (int j = 0; j < 4; ++j) {
        int row = mt * 16 + (g << 2) + j;
        ks[row * 256 + ((((col >> 3) ^ (row & 7)) << 3)) + (col & 7)] =
            (f16_t)(acc1[mt][nt][j] + bias);
      }
  }
  __syncthreads();

  // ---- GEMM2: pass 0 -> Kh (Wk), pass 1 -> Vh (Wv)
#pragma unroll
  for (int p = 0; p < 2; ++p) {
    const f16_t* wsec = w3 + ((size_t)(p + 1) << 16);  // skip Wq block
    const float* bsec = p ? bv : bk;
    f16_t* obuf = p ? vhg : khg;
    f32x4 acc[4][2];
#pragma unroll
    for (int mt = 0; mt < 4; ++mt)
#pragma unroll
      for (int nt = 0; nt < 2; ++nt) acc[mt][nt] = zero4();
#pragma unroll
    for (int kt = 0; kt < 8; ++kt) {
      f16x8 a[4];
#pragma unroll
      for (int mt = 0; mt < 4; ++mt) {
        int row = mt * 16 + m16;
        a[mt] = *(const f16x8*)&ks[row * 256 + ((((kt << 2) + g) ^ (row & 7)) << 3)];
      }
#pragma unroll
      for (int nt = 0; nt < 2; ++nt) {
        int col = wv_ * 32 + nt * 16 + m16;
        f16x8 b = *(const f16x8*)&wsec[(size_t)col * 256 + (kt << 5) + (g << 3)];
#pragma unroll
        for (int mt = 0; mt < 4; ++mt) acc[mt][nt] = MFMA16(a[mt], b, acc[mt][nt]);
      }
    }
#pragma unroll
    for (int nt = 0; nt < 2; ++nt) {
      int col = wv_ * 32 + nt * 16 + m16;
      float bias = bsec[col];
#pragma unroll
      for (int mt = 0; mt < 4; ++mt)
#pragma unroll
        for (int j = 0; j < 4; ++j) {
          int row = mt * 16 + (g << 2) + j;
          int e = ebase + row;
          if (e < E) obuf[(size_t)e * 256 + col] = (f16_t)(acc[mt][nt][j] + bias);
        }
    }
  }
}

// ---------------------------------------------------------------------------
// k_agg: one wave per dst node. Lane owns 4 channels (head = lane>>3).
// Softmax without max-shift (scores are O(+-35); exp(s) stays in f32 range and
// the normalized ratio is mathematically identical to the reference).
// Fused: segment softmax + weighted V sum + relu + LayerNorm.
// ---------------------------------------------------------------------------
__global__ __launch_bounds__(256) void k_agg(
    const float* __restrict__ qhd, const f16_t* __restrict__ khs,
    const f16_t* __restrict__ vhs, const f16_t* __restrict__ khg,
    const f16_t* __restrict__ vhg, const int* __restrict__ rs,
    const int* __restrict__ csr, const float* __restrict__ lng,
    const float* __restrict__ lnb, float* __restrict__ out, int D) {
  const int lane = threadIdx.x & 63;
  const int d = blockIdx.x * 4 + (threadIdx.x >> 6);
  if (d >= D) return;
  const int c0 = lane * 4;

  float qh0, qh1, qh2, qh3;
  {
    float4 v = *(const float4*)(qhd + (size_t)d * 256 + c0);
    qh0 = v.x; qh1 = v.y; qh2 = v.z; qh3 = v.w;
  }

  // self-loop term
  float den, a0, a1, a2, a3;
  {
    f16x4 ku = *(const f16x4*)(khs + (size_t)d * 256 + c0);
    f16x4 vu = *(const f16x4*)(vhs + (size_t)d * 256 + c0);
    float s = qh0 * (float)ku[0] + qh1 * (float)ku[1] + qh2 * (float)ku[2] + qh3 * (float)ku[3];
    s += __shfl_xor(s, 1); s += __shfl_xor(s, 2); s += __shfl_xor(s, 4);
    s = (s > 0.f) ? s : 0.2f * s;
    float ee = __expf(s);
    den = ee;
    a0 = ee * (float)vu[0]; a1 = ee * (float)vu[1];
    a2 = ee * (float)vu[2]; a3 = ee * (float)vu[3];
  }

  const int beg = rs[d], end = rs[d + 1];
  f16x4 kN, vN;
  if (beg < end) {
    int e = csr[beg];
    kN = *(const f16x4*)(khg + (size_t)e * 256 + c0);
    vN = *(const f16x4*)(vhg + (size_t)e * 256 + c0);
  }
  for (int idx = beg; idx < end; ++idx) {
    f16x4 ku = kN, vu = vN;
    if (idx + 1 < end) {  // 1-deep prefetch of next edge's rows
      int e = csr[idx + 1];
      kN = *(const f16x4*)(khg + (size_t)e * 256 + c0);
      vN = *(const f16x4*)(vhg + (size_t)e * 256 + c0);
    }
    float s = qh0 * (float)ku[0] + qh1 * (float)ku[1] + qh2 * (float)ku[2] + qh3 * (float)ku[3];
    s += __shfl_xor(s, 1); s += __shfl_xor(s, 2); s += __shfl_xor(s, 4);
    s = (s > 0.f) ? s : 0.2f * s;
    float ee = __expf(s);
    den += ee;
    a0 = fmaf(ee, (float)vu[0], a0); a1 = fmaf(ee, (float)vu[1], a1);
    a2 = fmaf(ee, (float)vu[2], a2); a3 = fmaf(ee, (float)vu[3], a3);
  }

  float x0 = fmaxf(a0 / den, 0.f), x1 = fmaxf(a1 / den, 0.f);
  float x2 = fmaxf(a2 / den, 0.f), x3 = fmaxf(a3 / den, 0.f);

  float s1 = x0 + x1 + x2 + x3;
#pragma unroll
  for (int m = 1; m < 64; m <<= 1) s1 += __shfl_xor(s1, m);
  float mu = s1 * (1.f / 256.f);
  float d0 = x0 - mu, d1 = x1 - mu, d2 = x2 - mu, d3 = x3 - mu;
  float s2 = d0 * d0 + d1 * d1 + d2 * d2 + d3 * d3;
#pragma unroll
  for (int m = 1; m < 64; m <<= 1) s2 += __shfl_xor(s2, m);
  float rstd = rsqrtf(s2 * (1.f / 256.f) + 1e-5f);

  float4 gg = *(const float4*)(lng + c0);
  float4 bb = *(const float4*)(lnb + c0);
  float4 o;
  o.x = d0 * rstd * gg.x + bb.x;
  o.y = d1 * rstd * gg.y + bb.y;
  o.z = d2 * rstd * gg.z + bb.z;
  o.w = d3 * rstd * gg.w + bb.w;
  *(float4*)(out + (size_t)d * 256 + c0) = o;
}

// ---------------------------------------------------------------------------
extern "C" void kernel_launch(void* const* d_in, const int* in_sizes, int n_in,
                              void* d_out, int out_size, void* d_ws,
                              size_t ws_size, hipStream_t stream) {
  const float* h       = (const float*)d_in[0];
  const float* f       = (const float*)d_in[1];
  const float* dt      = (const float*)d_in[2];
  const float* wq_lin  = (const float*)d_in[3];
  const float* bq_lin  = (const float*)d_in[4];
  const float* wkv_lin = (const float*)d_in[5];
  const float* bkv_lin = (const float*)d_in[6];
  const float* wq      = (const float*)d_in[7];
  const float* bq      = (const float*)d_in[8];
  const float* wk      = (const float*)d_in[9];
  const float* bk      = (const float*)d_in[10];
  const float* wv      = (const float*)d_in[11];
  const float* bv      = (const float*)d_in[12];
  const float* lng     = (const float*)d_in[13];
  const float* lnb     = (const float*)d_in[14];
  const int*   dst     = (const int*)d_in[15];

  const int S = in_sizes[0] / 128;
  const int E = in_sizes[2];
  const int D = S - E;
  float* out = (float*)d_out;

  // workspace carve-out (256B aligned)
  char* p = (char*)d_ws;
  size_t off = 0;
  auto take = [&](size_t bytes) -> char* {
    char* r = p + off;
    off += (bytes + 255) & ~(size_t)255;
    return r;
  };
  f16_t* wkv_pad = (f16_t*)take((size_t)98304 * 2);
  f16_t* wq1     = (f16_t*)take((size_t)32768 * 2);
  f16_t* w3      = (f16_t*)take((size_t)196608 * 2);
  float* bqe     = (float*)take((size_t)256 * 4);
  float* qhd     = (float*)take((size_t)D * 256 * 4);
  f16_t* khs     = (f16_t*)take((size_t)D * 256 * 2);
  f16_t* vhs     = (f16_t*)take((size_t)D * 256 * 2);
  f16_t* khg     = (f16_t*)take((size_t)E * 256 * 2);
  f16_t* vhg     = (f16_t*)take((size_t)E * 256 * 2);
  int*   rs      = (int*)  take((size_t)(D + 1) * 4);
  int*   cur     = (int*)  take((size_t)D * 4);
  int*   csr     = (int*)  take((size_t)E * 4);

  if (off > ws_size) {
    // workspace too small for this plan: emit unmistakable sentinel
    k_sentinel<<<(out_size + 255) / 256, 256, 0, stream>>>(out, out_size);
    return;
  }

  hipMemsetAsync(rs, 0, (size_t)(D + 1) * 4, stream);
  k_prep<<<1281, 256, 0, stream>>>(wq_lin, bq_lin, wkv_lin, wq, wk, wv,
                                   wkv_pad, wq1, w3, bqe);
  k_hist<<<(E + 255) / 256, 256, 0, stream>>>(dst, rs, E);
  k_scan<<<1, 1024, 0, stream>>>(rs, cur, D);
  k_scatter<<<(E + 255) / 256, 256, 0, stream>>>(dst, cur, csr, E);
  k_q<<<(D + 63) / 64, 512, 0, stream>>>(h, bqe, bq, bk, bv, wq1, w3, qhd, khs,
                                         vhs, D);
  k_kv<<<(E + 63) / 64, 512, 0, stream>>>(h, f, dt, bkv_lin, bk, bv, wkv_pad,
                                          w3, khg, vhg, D, E);
  k_agg<<<(D + 3) / 4, 256, 0, stream>>>(qhd, khs, vhs, khg, vhg, rs, csr, lng,
                                         lnb, out, D);
}